// Round 7
// baseline (25.450 us; speedup 1.0000x reference)
//
#include <hip/hip_runtime.h>

// Problem constants (fixed by setup_inputs: N=4096, box=50, cutoff=5)
#define N_ATOMS 4096
#define CUTOFF_SQ 25.0f

typedef float f4 __attribute__((ext_vector_type(4)));

// R6 restructure: the output is ~99.8% zeros (avg ~17 neighbors/atom within
// 5A of 4096 cols). Writing 64 MiB of mostly-zeros from the kernel hit a
// ~16us wall across every store schedule (R1/R3/R5). Instead:
//   1) hipMemsetAsync zeroes d_out at rocclr-fill speed (~6.5 TB/s proven)
//   2) this kernel computes upper-triangle pairs and scatter-stores ONLY
//      the ~35k nonzero entries (predicated dword stores, ~140KB traffic)
// Stream order guarantees the scatter lands after the fill.
__global__ __launch_bounds__(256) void pairdist_scatter(
    const float* __restrict__ q,      // [N,3] positions
    const float* __restrict__ cell,   // [3] box lengths
    float* __restrict__ out)          // [N,N] output (pre-zeroed)
{
    const int tid = blockIdx.x * blockDim.x + threadIdx.x;  // 0 .. N*N/4-1
    const int row = tid >> 10;            // 1024 threads per row; wave-uniform
    const int j0  = (tid & 1023) << 2;    // 4 consecutive cols

    // Entire 4-col strip strictly below the diagonal: nothing to write.
    if (j0 + 4 <= row) return;

    const float cx = cell[0], cy = cell[1], cz = cell[2];

    // Row position: wave-uniform address -> scalar loads.
    const float xr = q[3 * row + 0];
    const float yr = q[3 * row + 1];
    const float zr = q[3 * row + 2];

    // Column positions: 4 atoms x 12B = 48B = 3 x float4, coalesced.
    union { f4 v[3]; float s[12]; } u;
    const f4* q4 = reinterpret_cast<const f4*>(q);
    const int colt = tid & 1023;
#pragma unroll
    for (int m = 0; m < 3; ++m) u.v[m] = q4[3 * colt + m];

#pragma unroll
    for (int k = 0; k < 4; ++k) {
        const int j = j0 + k;
        // min-image |wrapped d| = min(|d|, c-|d|) (bit-exact; absmax==0
        // verified in R1-R5)
        float dx = fabsf(u.s[3 * k + 0] - xr); dx = fminf(dx, cx - dx);
        float dy = fabsf(u.s[3 * k + 1] - yr); dy = fminf(dy, cy - dy);
        float dz = fabsf(u.s[3 * k + 2] - zr); dz = fminf(dz, cz - dz);
        const float d2 = fmaf(dz, dz, fmaf(dy, dy, dx * dx));
        // j==row -> d2==0 -> excluded by d2!=0; so j>=row suffices for triu.
        const bool keep = (j >= row) & (d2 < CUTOFF_SQ) & (d2 != 0.0f);
        if (keep) out[(size_t)row * N_ATOMS + j] = d2;
    }
}

extern "C" void kernel_launch(void* const* d_in, const int* in_sizes, int n_in,
                              void* d_out, int out_size, void* d_ws, size_t ws_size,
                              hipStream_t stream) {
    const float* q    = (const float*)d_in[0];
    const float* cell = (const float*)d_in[1];
    float* out = (float*)d_out;

    // Phase 1: zero the whole output at hardware-fill speed.
    const size_t out_bytes = (size_t)N_ATOMS * N_ATOMS * sizeof(float);
    hipMemsetAsync(d_out, 0, out_bytes, stream);

    // Phase 2: scatter the ~35k nonzero squared distances (upper triangle).
    const int total_threads = (N_ATOMS * N_ATOMS) / 4;
    pairdist_scatter<<<total_threads / 256, 256, 0, stream>>>(q, cell, out);
}

// Round 8
// 20.252 us; speedup vs baseline: 1.2567x; 1.2567x over previous
//
#include <hip/hip_runtime.h>

// Problem constants (fixed by setup_inputs: N=4096, box=50, cutoff=5)
#define N_ATOMS 4096
#define CUTOFF_SQ 25.0f

typedef float f4 __attribute__((ext_vector_type(4)));

// R7: persistent-style grid. Same per-thread tile as R3 (8 rows x 4 cols,
// one dense float4 store per row -> 1KB dense wave stores), but only
// 512 blocks x 256 threads (2 blocks/CU, 2048 waves -- 4x fewer than R3).
// Each thread processes 4 consecutive 8-row groups (32 rows total), reusing
// its 48B column data 8x. Store work is uniform across blocks (zero tiles
// still store zeros; only compute is skipped), so the exactly-resident grid
// has no store-load imbalance.
// Regular stores (R4: nt hurts). d2!=0 dropped (d2==0 -> both write +0.0).
__global__ __launch_bounds__(256) void pairdist_kernel(
    const float* __restrict__ q,      // [N,3] positions
    const float* __restrict__ cell,   // [3] box lengths
    float* __restrict__ out)          // [N,N] output
{
    const int g = blockIdx.x >> 2;                           // 0..127 row-band (32 rows)
    const int colt = ((blockIdx.x & 3) << 8) + threadIdx.x;  // 0..1023
    const int j0 = colt << 2;                                // first col

    const float cx = cell[0], cy = cell[1], cz = cell[2];

    // Column positions: 4 atoms x 12B = 48B = 3 x float4 (L1-resident).
    union { f4 v[3]; float s[12]; } u;
    const f4* q4 = reinterpret_cast<const f4*>(q);
#pragma unroll
    for (int m = 0; m < 3; ++m) u.v[m] = q4[3 * colt + m];

#pragma unroll
    for (int s = 0; s < 4; ++s) {
        const int i0 = (g << 5) + (s << 3);                  // 8-row group base
        float* outp = out + (size_t)i0 * N_ATOMS + j0;

        // Tile fully below the diagonal: dense zero streaming, no compute.
        if (j0 + 4 <= i0) {
            const f4 z = {0.f, 0.f, 0.f, 0.f};
#pragma unroll
            for (int r = 0; r < 8; ++r)
                *reinterpret_cast<f4*>(outp + (size_t)r * N_ATOMS) = z;
            continue;
        }

        // Row positions (block-uniform address -> scalar loads).
        const float* qi = q + 3 * i0;
        float xi[8], yi[8], zi[8];
#pragma unroll
        for (int r = 0; r < 8; ++r) {
            xi[r] = qi[3 * r + 0];
            yi[r] = qi[3 * r + 1];
            zi[r] = qi[3 * r + 2];
        }

        if (j0 >= i0 + 8) {
            // Strictly above the diagonal for all 8 rows: no triu predicate.
#pragma unroll
            for (int r = 0; r < 8; ++r) {
                const float xr = xi[r], yr = yi[r], zr = zi[r];
                float res[4];
#pragma unroll
                for (int k = 0; k < 4; ++k) {
                    float dx = fabsf(u.s[3 * k + 0] - xr); dx = fminf(dx, cx - dx);
                    float dy = fabsf(u.s[3 * k + 1] - yr); dy = fminf(dy, cy - dy);
                    float dz = fabsf(u.s[3 * k + 2] - zr); dz = fminf(dz, cz - dz);
                    const float d2 = fmaf(dz, dz, fmaf(dy, dy, dx * dx));
                    res[k] = (d2 < CUTOFF_SQ) ? d2 : 0.0f;
                }
                f4 v = {res[0], res[1], res[2], res[3]};
                *reinterpret_cast<f4*>(outp + (size_t)r * N_ATOMS) = v;
            }
        } else {
            // Diagonal band: full triu predicate.
#pragma unroll
            for (int r = 0; r < 8; ++r) {
                const float xr = xi[r], yr = yi[r], zr = zi[r];
                const int ir = i0 + r;
                float res[4];
#pragma unroll
                for (int k = 0; k < 4; ++k) {
                    float dx = fabsf(u.s[3 * k + 0] - xr); dx = fminf(dx, cx - dx);
                    float dy = fabsf(u.s[3 * k + 1] - yr); dy = fminf(dy, cy - dy);
                    float dz = fabsf(u.s[3 * k + 2] - zr); dz = fminf(dz, cz - dz);
                    const float d2 = fmaf(dz, dz, fmaf(dy, dy, dx * dx));
                    const bool keep = (d2 < CUTOFF_SQ) & ((j0 + k) >= ir);
                    res[k] = keep ? d2 : 0.0f;
                }
                f4 v = {res[0], res[1], res[2], res[3]};
                *reinterpret_cast<f4*>(outp + (size_t)r * N_ATOMS) = v;
            }
        }
    }
}

extern "C" void kernel_launch(void* const* d_in, const int* in_sizes, int n_in,
                              void* d_out, int out_size, void* d_ws, size_t ws_size,
                              hipStream_t stream) {
    const float* q    = (const float*)d_in[0];
    const float* cell = (const float*)d_in[1];
    float* out = (float*)d_out;

    // 128 row-bands (32 rows each) x 4 col-segments = 512 blocks (2/CU).
    pairdist_kernel<<<512, 256, 0, stream>>>(q, cell, out);
}